// Round 14
// baseline (375.490 us; speedup 1.0000x reference)
//
#include <hip/hip_runtime.h>
#include <hip/hip_cooperative_groups.h>

namespace cg = cooperative_groups;

// LocNet2d on MFMA fp16. Preferred: 2 dispatches (l1 + cooperative mega with
// grid.sync between gemm0/reduce2/gemm1/head). Fallback (if cooperative launch
// fails): l1 + 4 separate R12-proven kernels.

typedef _Float16 f16;
typedef _Float16 half8 __attribute__((ext_vector_type(8)));
typedef _Float16 half4 __attribute__((ext_vector_type(4)));
typedef float f32x4 __attribute__((ext_vector_type(4)));

#define SWZ(r, c) ((((r) << 6) + (c)) ^ (((r) & 7) << 3))
#define SWZL(r, c) ((((r) << 10) + (c)) ^ (((r) & 7) << 3))

#define GLOAD_LDS16(G, L)                                                     \
  __builtin_amdgcn_global_load_lds(                                           \
      (const __attribute__((address_space(1))) void*)(G),                     \
      (__attribute__((address_space(3))) void*)(L), 16, 0, 0)

__global__ __launch_bounds__(256) void l1_mfma(const float* __restrict__ x,
                                               const float* __restrict__ w1,
                                               f16* __restrict__ A2) {
  const int o0 = blockIdx.x << 5;
  const int s2 = blockIdx.y;
  const int b0 = blockIdx.z << 5;
  const int p2 = s2 >> 1, q2 = s2 & 1;
  __shared__ __align__(16) f16 Xs[32 * 1024];  // 64 KB
  __shared__ __align__(16) f16 Ws[32 * 1024];  // 64 KB
  const int t = threadIdx.x;
#pragma unroll
  for (int i = 0; i < 8; ++i) {
    int e = (i << 8) + t;
    int row = e >> 6, rem = e & 63, g = rem >> 2, j = rem & 3;
    half4 z = {};
    *(half4*)&Xs[SWZL(row, g * 64 + 48 + j * 4)] = z;
    *(half4*)&Ws[SWZL(row, g * 64 + 48 + j * 4)] = z;
  }
#pragma unroll
  for (int i = 0; i < 24; ++i) {
    int fl = (i << 8) + t;
    int b = fl / 192, rem = fl % 192;
    int c = rem >> 6, rem2 = rem & 63;
    int a = rem2 >> 4, fi = (rem2 >> 2) & 3, bq = rem2 & 3;
    float4 v = *(const float4*)(x + ((size_t)(b0 + b) * 3 + c) * 1024 +
                                (p2 * 16 + a * 4 + fi) * 32 + q2 * 16 + bq * 4);
    half4 h;
    h[0] = (f16)v.x; h[1] = (f16)v.y; h[2] = (f16)v.z; h[3] = (f16)v.w;
    *(half4*)&Xs[SWZL(b, (a * 4 + bq) * 64 + c * 16 + fi * 4)] = h;
  }
#pragma unroll
  for (int i = 0; i < 24; ++i) {
    int fl = (i << 8) + t;
    int o = fl / 192, rem = fl % 192;
    int c = rem >> 6, rem2 = rem & 63;
    int g = rem2 >> 2, f4 = rem2 & 3;
    float4 v = *(const float4*)(w1 + (size_t)(o0 + o) * 3072 + c * 1024 +
                                (p2 * 4 + (g >> 2)) * 128 + (q2 * 4 + (g & 3)) * 16 + f4 * 4);
    half4 h;
    h[0] = (f16)v.x; h[1] = (f16)v.y; h[2] = (f16)v.z; h[3] = (f16)v.w;
    *(half4*)&Ws[SWZL(o, g * 64 + c * 16 + f4 * 4)] = h;
  }
  __syncthreads();

  const int wv = t >> 6, ln = t & 63;
  const int bw = wv >> 1, ow = wv & 1;
  const int frow = ln & 15, fr4 = ln >> 4;
  f32x4 acc[16] = {};
#pragma unroll
  for (int g = 0; g < 16; ++g) {
#pragma unroll
    for (int ks = 0; ks < 2; ++ks) {
      half8 a = *(const half8*)&Xs[SWZL(bw * 16 + frow, g * 64 + ks * 32 + fr4 * 8)];
      half8 b = *(const half8*)&Ws[SWZL(ow * 16 + frow, g * 64 + ks * 32 + fr4 * 8)];
      acc[g] = __builtin_amdgcn_mfma_f32_16x16x32_f16(a, b, acc[g], 0, 0, 0);
    }
  }
  f16* A2b = A2 + (size_t)s2 * 128 * 8192;
#pragma unroll
  for (int r = 0; r < 4; ++r) {
    int b = b0 + bw * 16 + fr4 * 4 + r;
    int o = o0 + ow * 16 + frow;
    f16 tmp[16];
#pragma unroll
    for (int g = 0; g < 16; ++g)
      tmp[g] = (f16)fmaxf(acc[g][r] * 0.14433756729740643f, 0.f);  // 1/sqrt(48)
    f16* dst = A2b + (size_t)b * 8192 + o * 16;
    *(half8*)dst = *(half8*)&tmp[0];
    *(half8*)(dst + 8) = *(half8*)&tmp[8];
  }
}

// ---------- R12-proven standalone GEMM kernels (fallback path) ----------
template <int MODE>
__global__ __launch_bounds__(256) void gemm_f16(const f16* __restrict__ A,
                                                const float* __restrict__ W,
                                                float* __restrict__ P) {
  __shared__ __align__(16) f16 As[2][128 * 64];
  __shared__ __align__(16) float Bs[2][64 * 64];
  const int t = threadIdx.x;
  const int bid = blockIdx.x;
  constexpr int AK = (MODE == 0) ? 8192 : 2048;
  constexpr int ITERS = (MODE == 0) ? 8 : 2;
  const int s = (MODE == 0) ? (bid >> 7) : 0;
  const int kc = (MODE == 0) ? ((bid >> 3) & 15) : (bid >> 3);
  const int n = bid & 7;
  const int kb0 = kc * (ITERS * 64);
  const f16* Ab = A + (size_t)(MODE == 0 ? s * 128 : 0) * AK + kb0;
  const int o0 = n << 6;
  const int wv = t >> 6, ln = t & 63;
  const int a_r = (ln >> 3), a_sg0 = ln & 7;
  const int b_r = (ln >> 4), b_sg0 = ln & 15;

#define STAGE(IT, BUF)                                                          \
  {                                                                             \
    _Pragma("unroll") for (int jj = 0; jj < 4; ++jj) {                          \
      int rbase = wv * 32 + jj * 8;                                             \
      int r = rbase + a_r;                                                      \
      int sg = a_sg0 ^ (r & 7);                                                 \
      GLOAD_LDS16(Ab + (size_t)r * AK + ((IT) << 6) + (sg << 3),                \
                  &As[BUF][rbase << 6]);                                        \
    }                                                                           \
    _Pragma("unroll") for (int jj = 0; jj < 4; ++jj) {                          \
      int rbase = wv * 16 + jj * 4;                                             \
      int r = rbase + b_r;                                                      \
      int sg = b_sg0 ^ (r & 7);                                                 \
      const float* gp;                                                          \
      if constexpr (MODE == 0) {                                                \
        int k = kb0 + ((IT) << 6) + (sg << 2);                                  \
        gp = W + (size_t)(o0 + r) * 32768 + ((k >> 4) << 6) + (s << 4) + (k & 15); \
      } else {                                                                  \
        gp = W + (size_t)(o0 + r) * 2048 + kb0 + ((IT) << 6) + (sg << 2);       \
      }                                                                         \
      GLOAD_LDS16(gp, &Bs[BUF][rbase << 6]);                                    \
    }                                                                           \
  }

  const int wr = wv >> 1, wc = wv & 1;
  const int frow = ln & 15, fr4 = ln >> 4;
  f32x4 acc[4][2] = {};

#define COMPUTE(BUF)                                                            \
  _Pragma("unroll") for (int ks = 0; ks < 2; ++ks) {                            \
    half8 a[4];                                                                 \
    _Pragma("unroll") for (int mi = 0; mi < 4; ++mi) {                          \
      int r = wr * 64 + mi * 16 + frow;                                         \
      int gl = ((ks << 2) + fr4) ^ (r & 7);                                     \
      a[mi] = *(const half8*)&As[BUF][(r << 6) + (gl << 3)];                    \
    }                                                                           \
    _Pragma("unroll") for (int ni = 0; ni < 2; ++ni) {                          \
      int r = wc * 32 + ni * 16 + frow;                                         \
      int s0 = (ks << 3) + (fr4 << 1);                                          \
      float4 f0 = *(const float4*)&Bs[BUF][(r << 6) + ((s0 ^ (r & 7)) << 2)];   \
      float4 f1 = *(const float4*)&Bs[BUF][(r << 6) + (((s0 + 1) ^ (r & 7)) << 2)]; \
      half8 hb;                                                                 \
      hb[0] = (f16)f0.x; hb[1] = (f16)f0.y; hb[2] = (f16)f0.z; hb[3] = (f16)f0.w; \
      hb[4] = (f16)f1.x; hb[5] = (f16)f1.y; hb[6] = (f16)f1.z; hb[7] = (f16)f1.w; \
      _Pragma("unroll") for (int mi = 0; mi < 4; ++mi)                          \
        acc[mi][ni] = __builtin_amdgcn_mfma_f32_16x16x32_f16(a[mi], hb, acc[mi][ni], 0, 0, 0); \
    }                                                                           \
  }

  STAGE(0, 0)
#pragma unroll
  for (int it = 0; it < ITERS; ++it) {
    const int cur = it & 1;
    if (it + 1 < ITERS) {
      STAGE(it + 1, cur ^ 1)
      asm volatile("s_waitcnt vmcnt(8)" ::: "memory");
    } else {
      asm volatile("s_waitcnt vmcnt(0)" ::: "memory");
    }
    __builtin_amdgcn_s_barrier();
    __builtin_amdgcn_sched_barrier(0);
    COMPUTE(cur)
    __builtin_amdgcn_sched_barrier(0);
    __builtin_amdgcn_s_barrier();
  }

  float* Pb = P + (size_t)(MODE == 0 ? (kc << 2) + s : kc) * 65536;
#pragma unroll
  for (int mi = 0; mi < 4; ++mi)
#pragma unroll
    for (int ni = 0; ni < 2; ++ni)
#pragma unroll
      for (int r = 0; r < 4; ++r) {
        int gm = wr * 64 + mi * 16 + fr4 * 4 + r;
        int gn = o0 + wc * 32 + ni * 16 + frow;
        Pb[(size_t)gm * 512 + gn] = acc[mi][ni][r];
      }
#undef STAGE
#undef COMPUTE
}

__device__ __forceinline__ void reduce2_body(int idx, const float* __restrict__ P2,
                                             f16* __restrict__ A3) {
  int og = idx & 127, b = idx >> 7;
  f16 outv[16];
#pragma unroll
  for (int s = 0; s < 4; ++s) {
    float4 a4 = {0.f, 0.f, 0.f, 0.f};
#pragma unroll
    for (int kc = 0; kc < 16; ++kc) {
      float4 v = *(const float4*)(P2 + (size_t)((kc << 2) + s) * 65536 + b * 512 + og * 4);
      a4.x += v.x; a4.y += v.y; a4.z += v.z; a4.w += v.w;
    }
    outv[0 * 4 + s] = (f16)fmaxf(a4.x * 0.011048543456039805f, 0.f);  // 1/sqrt(8192)
    outv[1 * 4 + s] = (f16)fmaxf(a4.y * 0.011048543456039805f, 0.f);
    outv[2 * 4 + s] = (f16)fmaxf(a4.z * 0.011048543456039805f, 0.f);
    outv[3 * 4 + s] = (f16)fmaxf(a4.w * 0.011048543456039805f, 0.f);
  }
  f16* dst = A3 + (size_t)b * 2048 + og * 16;
  *(half8*)dst = *(half8*)&outv[0];
  *(half8*)(dst + 8) = *(half8*)&outv[8];
}

__global__ __launch_bounds__(256) void reduce2(const float* __restrict__ P2,
                                               f16* __restrict__ A3) {
  reduce2_body(blockIdx.x * 256 + threadIdx.x, P2, A3);
}

__device__ __forceinline__ float head_partial(int b, int t, const float* __restrict__ P3,
                                              const float* __restrict__ beta) {
  float acc = 0.f;
#pragma unroll
  for (int oi = 0; oi < 2; ++oi) {
    int o = (oi << 8) + t;
    float v = 0.f;
#pragma unroll
    for (int kc = 0; kc < 16; ++kc) v += P3[(size_t)kc * 65536 + b * 512 + o];
    acc += fmaxf(v * 0.022097086912079608f, 0.f) * beta[o];  // 1/sqrt(2048)
  }
#pragma unroll
  for (int off = 32; off > 0; off >>= 1) acc += __shfl_down(acc, off);
  return acc;
}

__global__ __launch_bounds__(256) void out_fused(const float* __restrict__ P3,
                                                 const float* __restrict__ beta,
                                                 float* __restrict__ out) {
  __shared__ float red[4];
  const int b = blockIdx.x, t = threadIdx.x;
  float acc = head_partial(b, t, P3, beta);
  if ((t & 63) == 0) red[t >> 6] = acc;
  __syncthreads();
  if (t == 0) out[b] = (red[0] + red[1] + red[2] + red[3]) * 0.044194173824159216f;
}

// ---------- cooperative mega (preferred path) ----------
__global__ __launch_bounds__(256) void mega(const f16* __restrict__ A2,
                                            const float* __restrict__ w2,
                                            float* __restrict__ P2,
                                            f16* __restrict__ A3,
                                            const float* __restrict__ w3,
                                            float* __restrict__ P3,
                                            const float* __restrict__ beta,
                                            float* __restrict__ out) {
  cg::grid_group grid = cg::this_grid();
  __shared__ __align__(16) f16 AsB[2][128 * 64];   // 32 KB
  __shared__ __align__(16) float BsB[2][64 * 64];  // 32 KB  (total exactly 64 KB)
  const int bid = blockIdx.x, t = threadIdx.x;

  // ---- Phase A: gemm0 (512 blocks, R12 decode) -> P2 ----
  {
    constexpr int AK = 8192, ITERS = 8;
    const int s = bid >> 7, kc = (bid >> 3) & 15, n = bid & 7;
    const int kb0 = kc * (ITERS * 64);
    const f16* Ab = A2 + (size_t)s * 128 * AK + kb0;
    const int o0 = n << 6;
    const int wv = t >> 6, ln = t & 63;
    const int a_r = (ln >> 3), a_sg0 = ln & 7;
    const int b_r = (ln >> 4), b_sg0 = ln & 15;

#define STAGE(IT, BUF)                                                          \
  {                                                                             \
    _Pragma("unroll") for (int jj = 0; jj < 4; ++jj) {                          \
      int rbase = wv * 32 + jj * 8;                                             \
      int r = rbase + a_r;                                                      \
      int sg = a_sg0 ^ (r & 7);                                                 \
      GLOAD_LDS16(Ab + (size_t)r * AK + ((IT) << 6) + (sg << 3),                \
                  &AsB[BUF][rbase << 6]);                                       \
    }                                                                           \
    _Pragma("unroll") for (int jj = 0; jj < 4; ++jj) {                          \
      int rbase = wv * 16 + jj * 4;                                             \
      int r = rbase + b_r;                                                      \
      int sg = b_sg0 ^ (r & 7);                                                 \
      int k = kb0 + ((IT) << 6) + (sg << 2);                                    \
      const float* gp = w2 + (size_t)(o0 + r) * 32768 + ((k >> 4) << 6) +       \
                        (s << 4) + (k & 15);                                    \
      GLOAD_LDS16(gp, &BsB[BUF][rbase << 6]);                                   \
    }                                                                           \
  }

    const int wr = wv >> 1, wc = wv & 1;
    const int frow = ln & 15, fr4 = ln >> 4;
    f32x4 acc[4][2] = {};

#define COMPUTE(BUF)                                                            \
  _Pragma("unroll") for (int ks = 0; ks < 2; ++ks) {                            \
    half8 a[4];                                                                 \
    _Pragma("unroll") for (int mi = 0; mi < 4; ++mi) {                          \
      int r = wr * 64 + mi * 16 + frow;                                         \
      int gl = ((ks << 2) + fr4) ^ (r & 7);                                     \
      a[mi] = *(const half8*)&AsB[BUF][(r << 6) + (gl << 3)];                   \
    }                                                                           \
    _Pragma("unroll") for (int ni = 0; ni < 2; ++ni) {                          \
      int r = wc * 32 + ni * 16 + frow;                                         \
      int s0 = (ks << 3) + (fr4 << 1);                                          \
      float4 f0 = *(const float4*)&BsB[BUF][(r << 6) + ((s0 ^ (r & 7)) << 2)];  \
      float4 f1 = *(const float4*)&BsB[BUF][(r << 6) + (((s0 + 1) ^ (r & 7)) << 2)]; \
      half8 hb;                                                                 \
      hb[0] = (f16)f0.x; hb[1] = (f16)f0.y; hb[2] = (f16)f0.z; hb[3] = (f16)f0.w; \
      hb[4] = (f16)f1.x; hb[5] = (f16)f1.y; hb[6] = (f16)f1.z; hb[7] = (f16)f1.w; \
      _Pragma("unroll") for (int mi = 0; mi < 4; ++mi)                          \
        acc[mi][ni] = __builtin_amdgcn_mfma_f32_16x16x32_f16(a[mi], hb, acc[mi][ni], 0, 0, 0); \
    }                                                                           \
  }

    STAGE(0, 0)
#pragma unroll
    for (int it = 0; it < ITERS; ++it) {
      const int cur = it & 1;
      if (it + 1 < ITERS) {
        STAGE(it + 1, cur ^ 1)
        asm volatile("s_waitcnt vmcnt(8)" ::: "memory");
      } else {
        asm volatile("s_waitcnt vmcnt(0)" ::: "memory");
      }
      __builtin_amdgcn_s_barrier();
      __builtin_amdgcn_sched_barrier(0);
      COMPUTE(cur)
      __builtin_amdgcn_sched_barrier(0);
      __builtin_amdgcn_s_barrier();
    }
#undef STAGE
#undef COMPUTE
    float* Pb = P2 + (size_t)((kc << 2) + s) * 65536;
#pragma unroll
    for (int mi = 0; mi < 4; ++mi)
#pragma unroll
      for (int ni = 0; ni < 2; ++ni)
#pragma unroll
        for (int r = 0; r < 4; ++r) {
          int gm = wr * 64 + mi * 16 + fr4 * 4 + r;
          int gn = o0 + wc * 32 + ni * 16 + frow;
          Pb[(size_t)gm * 512 + gn] = acc[mi][ni][r];
        }
  }
  __threadfence();
  grid.sync();

  // ---- Phase B: reduce2 (64 blocks) ----
  if (bid < 64) reduce2_body(bid * 256 + t, P2, A3);
  __threadfence();
  grid.sync();

  // ---- Phase C: gemm1 (128 blocks, splitK=16, ITERS=2) -> P3 ----
  if (bid < 128) {
    constexpr int AK = 2048, ITERS = 2;
    const int kc = bid >> 3, n = bid & 7;
    const int kb0 = kc * (ITERS * 64);
    const f16* Ab = A3 + kb0;
    const int o0 = n << 6;
    const int wv = t >> 6, ln = t & 63;
    const int a_r = (ln >> 3), a_sg0 = ln & 7;
    const int b_r = (ln >> 4), b_sg0 = ln & 15;

#define STAGE(IT, BUF)                                                          \
  {                                                                             \
    _Pragma("unroll") for (int jj = 0; jj < 4; ++jj) {                          \
      int rbase = wv * 32 + jj * 8;                                             \
      int r = rbase + a_r;                                                      \
      int sg = a_sg0 ^ (r & 7);                                                 \
      GLOAD_LDS16(Ab + (size_t)r * AK + ((IT) << 6) + (sg << 3),                \
                  &AsB[BUF][rbase << 6]);                                       \
    }                                                                           \
    _Pragma("unroll") for (int jj = 0; jj < 4; ++jj) {                          \
      int rbase = wv * 16 + jj * 4;                                             \
      int r = rbase + b_r;                                                      \
      int sg = b_sg0 ^ (r & 7);                                                 \
      const float* gp = w3 + (size_t)(o0 + r) * 2048 + kb0 + ((IT) << 6) + (sg << 2); \
      GLOAD_LDS16(gp, &BsB[BUF][rbase << 6]);                                   \
    }                                                                           \
  }

    const int wr = wv >> 1, wc = wv & 1;
    const int frow = ln & 15, fr4 = ln >> 4;
    f32x4 acc[4][2] = {};

#define COMPUTE(BUF)                                                            \
  _Pragma("unroll") for (int ks = 0; ks < 2; ++ks) {                            \
    half8 a[4];                                                                 \
    _Pragma("unroll") for (int mi = 0; mi < 4; ++mi) {                          \
      int r = wr * 64 + mi * 16 + frow;                                         \
      int gl = ((ks << 2) + fr4) ^ (r & 7);                                     \
      a[mi] = *(const half8*)&AsB[BUF][(r << 6) + (gl << 3)];                   \
    }                                                                           \
    _Pragma("unroll") for (int ni = 0; ni < 2; ++ni) {                          \
      int r = wc * 32 + ni * 16 + frow;                                         \
      int s0 = (ks << 3) + (fr4 << 1);                                          \
      float4 f0 = *(const float4*)&BsB[BUF][(r << 6) + ((s0 ^ (r & 7)) << 2)];  \
      float4 f1 = *(const float4*)&BsB[BUF][(r << 6) + (((s0 + 1) ^ (r & 7)) << 2)]; \
      half8 hb;                                                                 \
      hb[0] = (f16)f0.x; hb[1] = (f16)f0.y; hb[2] = (f16)f0.z; hb[3] = (f16)f0.w; \
      hb[4] = (f16)f1.x; hb[5] = (f16)f1.y; hb[6] = (f16)f1.z; hb[7] = (f16)f1.w; \
      _Pragma("unroll") for (int mi = 0; mi < 4; ++mi)                          \
        acc[mi][ni] = __builtin_amdgcn_mfma_f32_16x16x32_f16(a[mi], hb, acc[mi][ni], 0, 0, 0); \
    }                                                                           \
  }

    STAGE(0, 0)
#pragma unroll
    for (int it = 0; it < ITERS; ++it) {
      const int cur = it & 1;
      if (it + 1 < ITERS) {
        STAGE(it + 1, cur ^ 1)
        asm volatile("s_waitcnt vmcnt(8)" ::: "memory");
      } else {
        asm volatile("s_waitcnt vmcnt(0)" ::: "memory");
      }
      __builtin_amdgcn_s_barrier();
      __builtin_amdgcn_sched_barrier(0);
      COMPUTE(cur)
      __builtin_amdgcn_sched_barrier(0);
      __builtin_amdgcn_s_barrier();
    }
#undef STAGE
#undef COMPUTE
    float* Pb = P3 + (size_t)kc * 65536;
#pragma unroll
    for (int mi = 0; mi < 4; ++mi)
#pragma unroll
      for (int ni = 0; ni < 2; ++ni)
#pragma unroll
        for (int r = 0; r < 4; ++r) {
          int gm = wr * 64 + mi * 16 + fr4 * 4 + r;
          int gn = o0 + wc * 32 + ni * 16 + frow;
          Pb[(size_t)gm * 512 + gn] = acc[mi][ni][r];
        }
  }
  __threadfence();
  grid.sync();

  // ---- Phase D: head (128 blocks) ----
  if (bid < 128) {
    float acc = head_partial(bid, t, P3, beta);
    float* red = (float*)AsB;  // reuse LDS (no extra allocation)
    if ((t & 63) == 0) red[t >> 6] = acc;
    __syncthreads();
    if (t == 0) out[bid] = (red[0] + red[1] + red[2] + red[3]) * 0.044194173824159216f;
  }
}

extern "C" void kernel_launch(void* const* d_in, const int* in_sizes, int n_in,
                              void* d_out, int out_size, void* d_ws, size_t ws_size,
                              hipStream_t stream) {
  const float* x    = (const float*)d_in[0];
  const float* w1   = (const float*)d_in[1];
  const float* w2   = (const float*)d_in[2];
  const float* w3   = (const float*)d_in[3];
  const float* beta = (const float*)d_in[4];
  float* out = (float*)d_out;

  char* wsb = (char*)d_ws;
  f16*   A2 = (f16*)wsb;                                     // 8 MiB
  float* P2 = (float*)(wsb + (8ull << 20));                  // 16 MiB
  f16*   A3 = (f16*)(wsb + (24ull << 20));                   // 0.5 MiB
  float* P3 = (float*)(wsb + (24ull << 20) + (1ull << 19));  // 4 MiB

  l1_mfma<<<dim3(16, 4, 4), 256, 0, stream>>>(x, w1, A2);

  void* args[] = {&A2, &w2, &P2, &A3, &w3, &P3, &beta, &out};
  hipError_t err = hipLaunchCooperativeKernel((void*)mega, dim3(512), dim3(256),
                                              args, 0, stream);
  if (err != hipSuccess) {  // fallback: R12-proven separate kernels
    gemm_f16<0><<<512, 256, 0, stream>>>(A2, w2, P2);
    reduce2<<<64, 256, 0, stream>>>(P2, A3);
    gemm_f16<1><<<128, 256, 0, stream>>>(A3, w3, P3);
    out_fused<<<128, 256, 0, stream>>>(P3, beta, out);
  }
}

// Round 15
// 126.991 us; speedup vs baseline: 2.9568x; 2.9568x over previous
//
#include <hip/hip_runtime.h>

// LocNet2d on MFMA fp16, 4 dispatches:
//   l1_mfma  (zeroes split-K counters, then R12-v3 per-region GEMM) -> A2
//   gemm0    (per-s GEMM K=8192, splitK=16, vmcnt(8) pipeline) -> P2; the LAST
//            block per n-column (atomic ctr==64) reduces P2 -> A3 (R12 reduce2 body)
//   gemm1    (K=2048, splitK=16) -> P3
//   out      (reduce P3 + head) -> out

typedef _Float16 f16;
typedef _Float16 half8 __attribute__((ext_vector_type(8)));
typedef _Float16 half4 __attribute__((ext_vector_type(4)));
typedef float f32x4 __attribute__((ext_vector_type(4)));

#define SWZ(r, c) ((((r) << 6) + (c)) ^ (((r) & 7) << 3))
#define SWZL(r, c) ((((r) << 10) + (c)) ^ (((r) & 7) << 3))

#define GLOAD_LDS16(G, L)                                                     \
  __builtin_amdgcn_global_load_lds(                                           \
      (const __attribute__((address_space(1))) void*)(G),                     \
      (__attribute__((address_space(3))) void*)(L), 16, 0, 0)

__global__ __launch_bounds__(256) void l1_mfma(const float* __restrict__ x,
                                               const float* __restrict__ w1,
                                               f16* __restrict__ A2,
                                               int* __restrict__ ctr) {
  const int t = threadIdx.x;
  if (blockIdx.x == 0 && blockIdx.y == 0 && blockIdx.z == 0 && t < 8)
    ctr[t] = 0;  // l1 completes before gemm0 launches (stream order) -> visible
  const int o0 = blockIdx.x << 5;
  const int s2 = blockIdx.y;
  const int b0 = blockIdx.z << 5;
  const int p2 = s2 >> 1, q2 = s2 & 1;
  __shared__ __align__(16) f16 Xs[32 * 1024];  // 64 KB
  __shared__ __align__(16) f16 Ws[32 * 1024];  // 64 KB
#pragma unroll
  for (int i = 0; i < 8; ++i) {
    int e = (i << 8) + t;
    int row = e >> 6, rem = e & 63, g = rem >> 2, j = rem & 3;
    half4 z = {};
    *(half4*)&Xs[SWZL(row, g * 64 + 48 + j * 4)] = z;
    *(half4*)&Ws[SWZL(row, g * 64 + 48 + j * 4)] = z;
  }
#pragma unroll
  for (int i = 0; i < 24; ++i) {
    int fl = (i << 8) + t;
    int b = fl / 192, rem = fl % 192;
    int c = rem >> 6, rem2 = rem & 63;
    int a = rem2 >> 4, fi = (rem2 >> 2) & 3, bq = rem2 & 3;
    float4 v = *(const float4*)(x + ((size_t)(b0 + b) * 3 + c) * 1024 +
                                (p2 * 16 + a * 4 + fi) * 32 + q2 * 16 + bq * 4);
    half4 h;
    h[0] = (f16)v.x; h[1] = (f16)v.y; h[2] = (f16)v.z; h[3] = (f16)v.w;
    *(half4*)&Xs[SWZL(b, (a * 4 + bq) * 64 + c * 16 + fi * 4)] = h;
  }
#pragma unroll
  for (int i = 0; i < 24; ++i) {
    int fl = (i << 8) + t;
    int o = fl / 192, rem = fl % 192;
    int c = rem >> 6, rem2 = rem & 63;
    int g = rem2 >> 2, f4 = rem2 & 3;
    float4 v = *(const float4*)(w1 + (size_t)(o0 + o) * 3072 + c * 1024 +
                                (p2 * 4 + (g >> 2)) * 128 + (q2 * 4 + (g & 3)) * 16 + f4 * 4);
    half4 h;
    h[0] = (f16)v.x; h[1] = (f16)v.y; h[2] = (f16)v.z; h[3] = (f16)v.w;
    *(half4*)&Ws[SWZL(o, g * 64 + c * 16 + f4 * 4)] = h;
  }
  __syncthreads();

  const int wv = t >> 6, ln = t & 63;
  const int bw = wv >> 1, ow = wv & 1;
  const int frow = ln & 15, fr4 = ln >> 4;
  f32x4 acc[16] = {};
#pragma unroll
  for (int g = 0; g < 16; ++g) {
#pragma unroll
    for (int ks = 0; ks < 2; ++ks) {
      half8 a = *(const half8*)&Xs[SWZL(bw * 16 + frow, g * 64 + ks * 32 + fr4 * 8)];
      half8 b = *(const half8*)&Ws[SWZL(ow * 16 + frow, g * 64 + ks * 32 + fr4 * 8)];
      acc[g] = __builtin_amdgcn_mfma_f32_16x16x32_f16(a, b, acc[g], 0, 0, 0);
    }
  }
  f16* A2b = A2 + (size_t)s2 * 128 * 8192;
#pragma unroll
  for (int r = 0; r < 4; ++r) {
    int b = b0 + bw * 16 + fr4 * 4 + r;
    int o = o0 + ow * 16 + frow;
    f16 tmp[16];
#pragma unroll
    for (int g = 0; g < 16; ++g)
      tmp[g] = (f16)fmaxf(acc[g][r] * 0.14433756729740643f, 0.f);  // 1/sqrt(48)
    f16* dst = A2b + (size_t)b * 8192 + o * 16;
    *(half8*)dst = *(half8*)&tmp[0];
    *(half8*)(dst + 8) = *(half8*)&tmp[8];
  }
}

// One (b, og) cell of the P2 -> A3 reduction (og in float4 units, 0..127).
__device__ __forceinline__ void reduce2_cell(int b, int og, const float* __restrict__ P2,
                                             f16* __restrict__ A3) {
  f16 outv[16];
#pragma unroll
  for (int s = 0; s < 4; ++s) {
    float4 a4 = {0.f, 0.f, 0.f, 0.f};
#pragma unroll
    for (int kc = 0; kc < 16; ++kc) {
      float4 v = *(const float4*)(P2 + (size_t)((kc << 2) + s) * 65536 + b * 512 + og * 4);
      a4.x += v.x; a4.y += v.y; a4.z += v.z; a4.w += v.w;
    }
    outv[0 * 4 + s] = (f16)fmaxf(a4.x * 0.011048543456039805f, 0.f);  // 1/sqrt(8192)
    outv[1 * 4 + s] = (f16)fmaxf(a4.y * 0.011048543456039805f, 0.f);
    outv[2 * 4 + s] = (f16)fmaxf(a4.z * 0.011048543456039805f, 0.f);
    outv[3 * 4 + s] = (f16)fmaxf(a4.w * 0.011048543456039805f, 0.f);
  }
  f16* dst = A3 + (size_t)b * 2048 + og * 16;
  *(half8*)dst = *(half8*)&outv[0];
  *(half8*)(dst + 8) = *(half8*)&outv[8];
}

// MODE 0: L2 (512 blocks, bid=s*128+kc*8+n) + fused last-block-per-n reduction.
// MODE 1: L3 (128 blocks, bid=kc*8+n).
template <int MODE>
__global__ __launch_bounds__(256) void gemm_f16(const f16* __restrict__ A,
                                                const float* __restrict__ W,
                                                float* __restrict__ P,
                                                f16* __restrict__ A3,
                                                int* __restrict__ ctr) {
  __shared__ __align__(16) f16 As[2][128 * 64];   // 32 KB
  __shared__ __align__(16) float Bs[2][64 * 64];  // 32 KB
  __shared__ int lastf;
  const int t = threadIdx.x;
  const int bid = blockIdx.x;
  constexpr int AK = (MODE == 0) ? 8192 : 2048;
  constexpr int ITERS = (MODE == 0) ? 8 : 2;
  const int s = (MODE == 0) ? (bid >> 7) : 0;
  const int kc = (MODE == 0) ? ((bid >> 3) & 15) : (bid >> 3);
  const int n = bid & 7;
  const int kb0 = kc * (ITERS * 64);
  const f16* Ab = A + (size_t)(MODE == 0 ? s * 128 : 0) * AK + kb0;
  const int o0 = n << 6;
  const int wv = t >> 6, ln = t & 63;
  const int a_r = (ln >> 3), a_sg0 = ln & 7;
  const int b_r = (ln >> 4), b_sg0 = ln & 15;

#define STAGE(IT, BUF)                                                          \
  {                                                                             \
    _Pragma("unroll") for (int jj = 0; jj < 4; ++jj) {                          \
      int rbase = wv * 32 + jj * 8;                                             \
      int r = rbase + a_r;                                                      \
      int sg = a_sg0 ^ (r & 7);                                                 \
      GLOAD_LDS16(Ab + (size_t)r * AK + ((IT) << 6) + (sg << 3),                \
                  &As[BUF][rbase << 6]);                                        \
    }                                                                           \
    _Pragma("unroll") for (int jj = 0; jj < 4; ++jj) {                          \
      int rbase = wv * 16 + jj * 4;                                             \
      int r = rbase + b_r;                                                      \
      int sg = b_sg0 ^ (r & 7);                                                 \
      const float* gp;                                                          \
      if constexpr (MODE == 0) {                                                \
        int k = kb0 + ((IT) << 6) + (sg << 2);                                  \
        gp = W + (size_t)(o0 + r) * 32768 + ((k >> 4) << 6) + (s << 4) + (k & 15); \
      } else {                                                                  \
        gp = W + (size_t)(o0 + r) * 2048 + kb0 + ((IT) << 6) + (sg << 2);       \
      }                                                                         \
      GLOAD_LDS16(gp, &Bs[BUF][rbase << 6]);                                    \
    }                                                                           \
  }

  const int wr = wv >> 1, wc = wv & 1;
  const int frow = ln & 15, fr4 = ln >> 4;
  f32x4 acc[4][2] = {};

#define COMPUTE(BUF)                                                            \
  _Pragma("unroll") for (int ks = 0; ks < 2; ++ks) {                            \
    half8 a[4];                                                                 \
    _Pragma("unroll") for (int mi = 0; mi < 4; ++mi) {                          \
      int r = wr * 64 + mi * 16 + frow;                                         \
      int gl = ((ks << 2) + fr4) ^ (r & 7);                                     \
      a[mi] = *(const half8*)&As[BUF][(r << 6) + (gl << 3)];                    \
    }                                                                           \
    _Pragma("unroll") for (int ni = 0; ni < 2; ++ni) {                          \
      int r = wc * 32 + ni * 16 + frow;                                         \
      int s0 = (ks << 3) + (fr4 << 1);                                          \
      float4 f0 = *(const float4*)&Bs[BUF][(r << 6) + ((s0 ^ (r & 7)) << 2)];   \
      float4 f1 = *(const float4*)&Bs[BUF][(r << 6) + (((s0 + 1) ^ (r & 7)) << 2)]; \
      half8 hb;                                                                 \
      hb[0] = (f16)f0.x; hb[1] = (f16)f0.y; hb[2] = (f16)f0.z; hb[3] = (f16)f0.w; \
      hb[4] = (f16)f1.x; hb[5] = (f16)f1.y; hb[6] = (f16)f1.z; hb[7] = (f16)f1.w; \
      _Pragma("unroll") for (int mi = 0; mi < 4; ++mi)                          \
        acc[mi][ni] = __builtin_amdgcn_mfma_f32_16x16x32_f16(a[mi], hb, acc[mi][ni], 0, 0, 0); \
    }                                                                           \
  }

  STAGE(0, 0)
#pragma unroll
  for (int it = 0; it < ITERS; ++it) {
    const int cur = it & 1;
    if (it + 1 < ITERS) {
      STAGE(it + 1, cur ^ 1)
      asm volatile("s_waitcnt vmcnt(8)" ::: "memory");
    } else {
      asm volatile("s_waitcnt vmcnt(0)" ::: "memory");
    }
    __builtin_amdgcn_s_barrier();
    __builtin_amdgcn_sched_barrier(0);
    COMPUTE(cur)
    __builtin_amdgcn_sched_barrier(0);
    __builtin_amdgcn_s_barrier();
  }

  float* Pb = P + (size_t)(MODE == 0 ? (kc << 2) + s : kc) * 65536;
#pragma unroll
  for (int mi = 0; mi < 4; ++mi)
#pragma unroll
    for (int ni = 0; ni < 2; ++ni)
#pragma unroll
      for (int r = 0; r < 4; ++r) {
        int gm = wr * 64 + mi * 16 + fr4 * 4 + r;
        int gn = o0 + wc * 32 + ni * 16 + frow;
        Pb[(size_t)gm * 512 + gn] = acc[mi][ni][r];
      }

  if constexpr (MODE == 0) {
    // last block per n-column (64 producers: 4 s x 16 kc) reduces P2 -> A3 cols of n
    __threadfence();  // release P2 stores
    if (t == 0) lastf = (atomicAdd(&ctr[n], 1) == 63) ? 1 : 0;
    __syncthreads();
    if (lastf) {
      __threadfence();  // acquire: all producers' P2 visible
      for (int idx = t; idx < 2048; idx += 256) {
        int ogl = idx & 15, b = idx >> 4;
        reduce2_cell(b, (n << 4) + ogl, P, A3);
      }
    }
  }
#undef STAGE
#undef COMPUTE
}

__device__ __forceinline__ float head_partial(int b, int t, const float* __restrict__ P3,
                                              const float* __restrict__ beta) {
  float acc = 0.f;
#pragma unroll
  for (int oi = 0; oi < 2; ++oi) {
    int o = (oi << 8) + t;
    float v = 0.f;
#pragma unroll
    for (int kc = 0; kc < 16; ++kc) v += P3[(size_t)kc * 65536 + b * 512 + o];
    acc += fmaxf(v * 0.022097086912079608f, 0.f) * beta[o];  // 1/sqrt(2048)
  }
#pragma unroll
  for (int off = 32; off > 0; off >>= 1) acc += __shfl_down(acc, off);
  return acc;
}

__global__ __launch_bounds__(256) void out_fused(const float* __restrict__ P3,
                                                 const float* __restrict__ beta,
                                                 float* __restrict__ out) {
  __shared__ float red[4];
  const int b = blockIdx.x, t = threadIdx.x;
  float acc = head_partial(b, t, P3, beta);
  if ((t & 63) == 0) red[t >> 6] = acc;
  __syncthreads();
  if (t == 0) out[b] = (red[0] + red[1] + red[2] + red[3]) * 0.044194173824159216f;
}

extern "C" void kernel_launch(void* const* d_in, const int* in_sizes, int n_in,
                              void* d_out, int out_size, void* d_ws, size_t ws_size,
                              hipStream_t stream) {
  const float* x    = (const float*)d_in[0];
  const float* w1   = (const float*)d_in[1];
  const float* w2   = (const float*)d_in[2];
  const float* w3   = (const float*)d_in[3];
  const float* beta = (const float*)d_in[4];
  float* out = (float*)d_out;

  char* wsb = (char*)d_ws;
  f16*   A2 = (f16*)wsb;                                     // 8 MiB
  float* P2 = (float*)(wsb + (8ull << 20));                  // 16 MiB
  f16*   A3 = (f16*)(wsb + (24ull << 20));                   // 0.5 MiB
  float* P3 = (float*)(wsb + (24ull << 20) + (1ull << 19));  // 4 MiB
  int*  ctr = (int*)(wsb + (28ull << 20) + (1ull << 19));    // 32 B

  l1_mfma<<<dim3(16, 4, 4), 256, 0, stream>>>(x, w1, A2, ctr);
  gemm_f16<0><<<512, 256, 0, stream>>>(A2, w2, P2, A3, ctr);
  gemm_f16<1><<<128, 256, 0, stream>>>(A3, w3, P3, nullptr, nullptr);
  out_fused<<<128, 256, 0, stream>>>(P3, beta, out);
}

// Round 16
// 49.626 us; speedup vs baseline: 7.5665x; 2.5590x over previous
//
#include <hip/hip_runtime.h>

// LocNet2d on MFMA fp16, 5 dispatches (R12 structure, proven 49.4us):
//   l1_mfma: block = 32b x 32o x one s2-cell x all 16 patches; Xs/Ws staged once;
//            coalesced 32-B A2 stores.  -> A2 fp16 [s][b][o*16+g]
//   gemm0:   per-s GEMM M=128,N=512,K=8192, splitK=16, K-step=64, dbuf LDS,
//            counted vmcnt(8) pipeline, global_load_lds w/ source-folded s-gather.
//            bid=s*128+kc*8+n -> XCD=n: all 64 blocks of an n-column co-resident
//            on one XCD -> w2 lines fetched once (do not change this mapping).
//   reduce2: float4 over (kc,s), coalesced 32-B A3 writes.
//   gemm1:   same structure, K=2048, splitK=16 -> P3
//   out:     reduce P3 + head.
// T5: s_setprio(1/0) around MFMA clusters.

typedef _Float16 f16;
typedef _Float16 half8 __attribute__((ext_vector_type(8)));
typedef _Float16 half4 __attribute__((ext_vector_type(4)));
typedef float f32x4 __attribute__((ext_vector_type(4)));

#define SWZ(r, c) ((((r) << 6) + (c)) ^ (((r) & 7) << 3))
#define SWZL(r, c) ((((r) << 10) + (c)) ^ (((r) & 7) << 3))

#define GLOAD_LDS16(G, L)                                                     \
  __builtin_amdgcn_global_load_lds(                                           \
      (const __attribute__((address_space(1))) void*)(G),                     \
      (__attribute__((address_space(3))) void*)(L), 16, 0, 0)

__global__ __launch_bounds__(256) void l1_mfma(const float* __restrict__ x,
                                               const float* __restrict__ w1,
                                               f16* __restrict__ A2) {
  const int o0 = blockIdx.x << 5;
  const int s2 = blockIdx.y;
  const int b0 = blockIdx.z << 5;
  const int p2 = s2 >> 1, q2 = s2 & 1;
  __shared__ __align__(16) f16 Xs[32 * 1024];  // 64 KB: [b][g*64 + c*16 + f]
  __shared__ __align__(16) f16 Ws[32 * 1024];  // 64 KB: [o][g*64 + c*16 + f]
  const int t = threadIdx.x;
#pragma unroll
  for (int i = 0; i < 8; ++i) {
    int e = (i << 8) + t;
    int row = e >> 6, rem = e & 63, g = rem >> 2, j = rem & 3;
    half4 z = {};
    *(half4*)&Xs[SWZL(row, g * 64 + 48 + j * 4)] = z;
    *(half4*)&Ws[SWZL(row, g * 64 + 48 + j * 4)] = z;
  }
#pragma unroll
  for (int i = 0; i < 24; ++i) {
    int fl = (i << 8) + t;
    int b = fl / 192, rem = fl % 192;
    int c = rem >> 6, rem2 = rem & 63;
    int a = rem2 >> 4, fi = (rem2 >> 2) & 3, bq = rem2 & 3;
    float4 v = *(const float4*)(x + ((size_t)(b0 + b) * 3 + c) * 1024 +
                                (p2 * 16 + a * 4 + fi) * 32 + q2 * 16 + bq * 4);
    half4 h;
    h[0] = (f16)v.x; h[1] = (f16)v.y; h[2] = (f16)v.z; h[3] = (f16)v.w;
    *(half4*)&Xs[SWZL(b, (a * 4 + bq) * 64 + c * 16 + fi * 4)] = h;
  }
#pragma unroll
  for (int i = 0; i < 24; ++i) {
    int fl = (i << 8) + t;
    int o = fl / 192, rem = fl % 192;
    int c = rem >> 6, rem2 = rem & 63;
    int g = rem2 >> 2, f4 = rem2 & 3;
    float4 v = *(const float4*)(w1 + (size_t)(o0 + o) * 3072 + c * 1024 +
                                (p2 * 4 + (g >> 2)) * 128 + (q2 * 4 + (g & 3)) * 16 + f4 * 4);
    half4 h;
    h[0] = (f16)v.x; h[1] = (f16)v.y; h[2] = (f16)v.z; h[3] = (f16)v.w;
    *(half4*)&Ws[SWZL(o, g * 64 + c * 16 + f4 * 4)] = h;
  }
  __syncthreads();

  const int wv = t >> 6, ln = t & 63;
  const int bw = wv >> 1, ow = wv & 1;
  const int frow = ln & 15, fr4 = ln >> 4;
  f32x4 acc[16] = {};
  __builtin_amdgcn_s_setprio(1);
#pragma unroll
  for (int g = 0; g < 16; ++g) {
#pragma unroll
    for (int ks = 0; ks < 2; ++ks) {
      half8 a = *(const half8*)&Xs[SWZL(bw * 16 + frow, g * 64 + ks * 32 + fr4 * 8)];
      half8 b = *(const half8*)&Ws[SWZL(ow * 16 + frow, g * 64 + ks * 32 + fr4 * 8)];
      acc[g] = __builtin_amdgcn_mfma_f32_16x16x32_f16(a, b, acc[g], 0, 0, 0);
    }
  }
  __builtin_amdgcn_s_setprio(0);
  f16* A2b = A2 + (size_t)s2 * 128 * 8192;
#pragma unroll
  for (int r = 0; r < 4; ++r) {
    int b = b0 + bw * 16 + fr4 * 4 + r;
    int o = o0 + ow * 16 + frow;
    f16 tmp[16];
#pragma unroll
    for (int g = 0; g < 16; ++g)
      tmp[g] = (f16)fmaxf(acc[g][r] * 0.14433756729740643f, 0.f);  // 1/sqrt(48)
    f16* dst = A2b + (size_t)b * 8192 + o * 16;
    *(half8*)dst = *(half8*)&tmp[0];
    *(half8*)(dst + 8) = *(half8*)&tmp[8];
  }
}

// MODE 0: L2 (w2 fp32 s-gather, 512 blocks). MODE 1: L3 (w3 fp32 contiguous, 128 blocks).
// Tile M=128 x N=64, K-step 64, double-buffered LDS, counted-vmcnt pipeline.
template <int MODE>
__global__ __launch_bounds__(256) void gemm_f16(const f16* __restrict__ A,
                                                const float* __restrict__ W,
                                                float* __restrict__ P) {
  __shared__ __align__(16) f16 As[2][128 * 64];   // 2 x 16 KB
  __shared__ __align__(16) float Bs[2][64 * 64];  // 2 x 16 KB
  const int t = threadIdx.x;
  const int bid = blockIdx.x;
  constexpr int AK = (MODE == 0) ? 8192 : 2048;
  constexpr int ITERS = (MODE == 0) ? 8 : 2;
  const int s = (MODE == 0) ? (bid >> 7) : 0;
  const int kc = (MODE == 0) ? ((bid >> 3) & 15) : (bid >> 3);
  const int n = bid & 7;
  const int kb0 = kc * (ITERS * 64);
  const f16* Ab = A + (size_t)(MODE == 0 ? s * 128 : 0) * AK + kb0;
  const int o0 = n << 6;
  const int wv = t >> 6, ln = t & 63;
  const int a_r = (ln >> 3), a_sg0 = ln & 7;
  const int b_r = (ln >> 4), b_sg0 = ln & 15;

#define STAGE(IT, BUF)                                                          \
  {                                                                             \
    _Pragma("unroll") for (int jj = 0; jj < 4; ++jj) {                          \
      int rbase = wv * 32 + jj * 8;                                             \
      int r = rbase + a_r;                                                      \
      int sg = a_sg0 ^ (r & 7);                                                 \
      GLOAD_LDS16(Ab + (size_t)r * AK + ((IT) << 6) + (sg << 3),                \
                  &As[BUF][rbase << 6]);                                        \
    }                                                                           \
    _Pragma("unroll") for (int jj = 0; jj < 4; ++jj) {                          \
      int rbase = wv * 16 + jj * 4;                                             \
      int r = rbase + b_r;                                                      \
      int sg = b_sg0 ^ (r & 7);                                                 \
      const float* gp;                                                          \
      if constexpr (MODE == 0) {                                                \
        int k = kb0 + ((IT) << 6) + (sg << 2);                                  \
        gp = W + (size_t)(o0 + r) * 32768 + ((k >> 4) << 6) + (s << 4) + (k & 15); \
      } else {                                                                  \
        gp = W + (size_t)(o0 + r) * 2048 + kb0 + ((IT) << 6) + (sg << 2);       \
      }                                                                         \
      GLOAD_LDS16(gp, &Bs[BUF][rbase << 6]);                                    \
    }                                                                           \
  }

  const int wr = wv >> 1, wc = wv & 1;
  const int frow = ln & 15, fr4 = ln >> 4;
  f32x4 acc[4][2] = {};

#define COMPUTE(BUF)                                                            \
  __builtin_amdgcn_s_setprio(1);                                                \
  _Pragma("unroll") for (int ks = 0; ks < 2; ++ks) {                            \
    half8 a[4];                                                                 \
    _Pragma("unroll") for (int mi = 0; mi < 4; ++mi) {                          \
      int r = wr * 64 + mi * 16 + frow;                                         \
      int gl = ((ks << 2) + fr4) ^ (r & 7);                                     \
      a[mi] = *(const half8*)&As[BUF][(r << 6) + (gl << 3)];                    \
    }                                                                           \
    _Pragma("unroll") for (int ni = 0; ni < 2; ++ni) {                          \
      int r = wc * 32 + ni * 16 + frow;                                         \
      int s0 = (ks << 3) + (fr4 << 1);                                          \
      float4 f0 = *(const float4*)&Bs[BUF][(r << 6) + ((s0 ^ (r & 7)) << 2)];   \
      float4 f1 = *(const float4*)&Bs[BUF][(r << 6) + (((s0 + 1) ^ (r & 7)) << 2)]; \
      half8 hb;                                                                 \
      hb[0] = (f16)f0.x; hb[1] = (f16)f0.y; hb[2] = (f16)f0.z; hb[3] = (f16)f0.w; \
      hb[4] = (f16)f1.x; hb[5] = (f16)f1.y; hb[6] = (f16)f1.z; hb[7] = (f16)f1.w; \
      _Pragma("unroll") for (int mi = 0; mi < 4; ++mi)                          \
        acc[mi][ni] = __builtin_amdgcn_mfma_f32_16x16x32_f16(a[mi], hb, acc[mi][ni], 0, 0, 0); \
    }                                                                           \
  }                                                                             \
  __builtin_amdgcn_s_setprio(0);

  STAGE(0, 0)
#pragma unroll
  for (int it = 0; it < ITERS; ++it) {
    const int cur = it & 1;
    if (it + 1 < ITERS) {
      STAGE(it + 1, cur ^ 1)
      asm volatile("s_waitcnt vmcnt(8)" ::: "memory");
    } else {
      asm volatile("s_waitcnt vmcnt(0)" ::: "memory");
    }
    __builtin_amdgcn_s_barrier();
    __builtin_amdgcn_sched_barrier(0);
    COMPUTE(cur)
    __builtin_amdgcn_sched_barrier(0);
    __builtin_amdgcn_s_barrier();
  }

  float* Pb = P + (size_t)(MODE == 0 ? (kc << 2) + s : kc) * 65536;
#pragma unroll
  for (int mi = 0; mi < 4; ++mi)
#pragma unroll
    for (int ni = 0; ni < 2; ++ni)
#pragma unroll
      for (int r = 0; r < 4; ++r) {
        int gm = wr * 64 + mi * 16 + fr4 * 4 + r;
        int gn = o0 + wc * 32 + ni * 16 + frow;
        Pb[(size_t)gm * 512 + gn] = acc[mi][ni][r];
      }
#undef STAGE
#undef COMPUTE
}

__global__ __launch_bounds__(256) void reduce2(const float* __restrict__ P2,
                                               f16* __restrict__ A3) {
  int idx = blockIdx.x * 256 + threadIdx.x;
  int og = idx & 127, b = idx >> 7;
  f16 outv[16];
#pragma unroll
  for (int s = 0; s < 4; ++s) {
    float4 acc = {0.f, 0.f, 0.f, 0.f};
#pragma unroll
    for (int kc = 0; kc < 16; ++kc) {
      float4 v = *(const float4*)(P2 + (size_t)((kc << 2) + s) * 65536 + b * 512 + og * 4);
      acc.x += v.x; acc.y += v.y; acc.z += v.z; acc.w += v.w;
    }
    outv[0 * 4 + s] = (f16)fmaxf(acc.x * 0.011048543456039805f, 0.f);  // 1/sqrt(8192)
    outv[1 * 4 + s] = (f16)fmaxf(acc.y * 0.011048543456039805f, 0.f);
    outv[2 * 4 + s] = (f16)fmaxf(acc.z * 0.011048543456039805f, 0.f);
    outv[3 * 4 + s] = (f16)fmaxf(acc.w * 0.011048543456039805f, 0.f);
  }
  f16* dst = A3 + (size_t)b * 2048 + og * 16;
  *(half8*)dst = *(half8*)&outv[0];
  *(half8*)(dst + 8) = *(half8*)&outv[8];
}

__global__ __launch_bounds__(256) void out_fused(const float* __restrict__ P3,
                                                 const float* __restrict__ beta,
                                                 float* __restrict__ out) {
  __shared__ float red[4];
  const int b = blockIdx.x, t = threadIdx.x;
  float acc = 0.f;
#pragma unroll
  for (int oi = 0; oi < 2; ++oi) {
    int o = (oi << 8) + t;
    float v = 0.f;
#pragma unroll
    for (int kc = 0; kc < 16; ++kc) v += P3[(size_t)kc * 65536 + b * 512 + o];
    acc += fmaxf(v * 0.022097086912079608f, 0.f) * beta[o];  // 1/sqrt(2048)
  }
#pragma unroll
  for (int off = 32; off > 0; off >>= 1) acc += __shfl_down(acc, off);
  if ((t & 63) == 0) red[t >> 6] = acc;
  __syncthreads();
  if (t == 0) out[b] = (red[0] + red[1] + red[2] + red[3]) * 0.044194173824159216f;
}

extern "C" void kernel_launch(void* const* d_in, const int* in_sizes, int n_in,
                              void* d_out, int out_size, void* d_ws, size_t ws_size,
                              hipStream_t stream) {
  const float* x    = (const float*)d_in[0];
  const float* w1   = (const float*)d_in[1];
  const float* w2   = (const float*)d_in[2];
  const float* w3   = (const float*)d_in[3];
  const float* beta = (const float*)d_in[4];
  float* out = (float*)d_out;

  char* wsb = (char*)d_ws;
  f16*   A2 = (f16*)wsb;                                     // 8 MiB
  float* P2 = (float*)(wsb + (8ull << 20));                  // 16 MiB
  f16*   A3 = (f16*)(wsb + (24ull << 20));                   // 0.5 MiB
  float* P3 = (float*)(wsb + (24ull << 20) + (1ull << 19));  // 4 MiB

  l1_mfma<<<dim3(16, 4, 4), 256, 0, stream>>>(x, w1, A2);
  gemm_f16<0><<<512, 256, 0, stream>>>(A2, w2, P2);
  reduce2<<<64, 256, 0, stream>>>(P2, A3);
  gemm_f16<1><<<128, 256, 0, stream>>>(A3, w3, P3);
  out_fused<<<128, 256, 0, stream>>>(P3, beta, out);
}

// Round 17
// 46.739 us; speedup vs baseline: 8.0338x; 1.0618x over previous
//
#include <hip/hip_runtime.h>

// LocNet2d on MFMA fp16, 5 dispatches:
//   l1_mfma: R12-v3 (s2-cell block, staged once, coalesced A2 stores)
//   gemm0:   per-s GEMM M=128,N=512,K=8192, splitK=16; TILE N=128 (256 blocks x
//            512 thr, 8 waves 2m x 4n) to halve redundant A2 re-staging;
//            K-step 64, dbuf LDS, counted vmcnt(6) pipeline, global_load_lds.
//   reduce2: float4 over (kc,s), coalesced 32-B A3 writes.
//   gemm1:   R12 config (128 blocks, N=64, splitK=16) -> P3
//   out:     reduce P3 + head.

typedef _Float16 f16;
typedef _Float16 half8 __attribute__((ext_vector_type(8)));
typedef _Float16 half4 __attribute__((ext_vector_type(4)));
typedef float f32x4 __attribute__((ext_vector_type(4)));

#define SWZ(r, c) ((((r) << 6) + (c)) ^ (((r) & 7) << 3))
#define SWZL(r, c) ((((r) << 10) + (c)) ^ (((r) & 7) << 3))

#define GLOAD_LDS16(G, L)                                                     \
  __builtin_amdgcn_global_load_lds(                                           \
      (const __attribute__((address_space(1))) void*)(G),                     \
      (__attribute__((address_space(3))) void*)(L), 16, 0, 0)

__global__ __launch_bounds__(256) void l1_mfma(const float* __restrict__ x,
                                               const float* __restrict__ w1,
                                               f16* __restrict__ A2) {
  const int o0 = blockIdx.x << 5;
  const int s2 = blockIdx.y;
  const int b0 = blockIdx.z << 5;
  const int p2 = s2 >> 1, q2 = s2 & 1;
  __shared__ __align__(16) f16 Xs[32 * 1024];  // 64 KB
  __shared__ __align__(16) f16 Ws[32 * 1024];  // 64 KB
  const int t = threadIdx.x;
#pragma unroll
  for (int i = 0; i < 8; ++i) {
    int e = (i << 8) + t;
    int row = e >> 6, rem = e & 63, g = rem >> 2, j = rem & 3;
    half4 z = {};
    *(half4*)&Xs[SWZL(row, g * 64 + 48 + j * 4)] = z;
    *(half4*)&Ws[SWZL(row, g * 64 + 48 + j * 4)] = z;
  }
#pragma unroll
  for (int i = 0; i < 24; ++i) {
    int fl = (i << 8) + t;
    int b = fl / 192, rem = fl % 192;
    int c = rem >> 6, rem2 = rem & 63;
    int a = rem2 >> 4, fi = (rem2 >> 2) & 3, bq = rem2 & 3;
    float4 v = *(const float4*)(x + ((size_t)(b0 + b) * 3 + c) * 1024 +
                                (p2 * 16 + a * 4 + fi) * 32 + q2 * 16 + bq * 4);
    half4 h;
    h[0] = (f16)v.x; h[1] = (f16)v.y; h[2] = (f16)v.z; h[3] = (f16)v.w;
    *(half4*)&Xs[SWZL(b, (a * 4 + bq) * 64 + c * 16 + fi * 4)] = h;
  }
#pragma unroll
  for (int i = 0; i < 24; ++i) {
    int fl = (i << 8) + t;
    int o = fl / 192, rem = fl % 192;
    int c = rem >> 6, rem2 = rem & 63;
    int g = rem2 >> 2, f4 = rem2 & 3;
    float4 v = *(const float4*)(w1 + (size_t)(o0 + o) * 3072 + c * 1024 +
                                (p2 * 4 + (g >> 2)) * 128 + (q2 * 4 + (g & 3)) * 16 + f4 * 4);
    half4 h;
    h[0] = (f16)v.x; h[1] = (f16)v.y; h[2] = (f16)v.z; h[3] = (f16)v.w;
    *(half4*)&Ws[SWZL(o, g * 64 + c * 16 + f4 * 4)] = h;
  }
  __syncthreads();

  const int wv = t >> 6, ln = t & 63;
  const int bw = wv >> 1, ow = wv & 1;
  const int frow = ln & 15, fr4 = ln >> 4;
  f32x4 acc[16] = {};
#pragma unroll
  for (int g = 0; g < 16; ++g) {
#pragma unroll
    for (int ks = 0; ks < 2; ++ks) {
      half8 a = *(const half8*)&Xs[SWZL(bw * 16 + frow, g * 64 + ks * 32 + fr4 * 8)];
      half8 b = *(const half8*)&Ws[SWZL(ow * 16 + frow, g * 64 + ks * 32 + fr4 * 8)];
      acc[g] = __builtin_amdgcn_mfma_f32_16x16x32_f16(a, b, acc[g], 0, 0, 0);
    }
  }
  f16* A2b = A2 + (size_t)s2 * 128 * 8192;
#pragma unroll
  for (int r = 0; r < 4; ++r) {
    int b = b0 + bw * 16 + fr4 * 4 + r;
    int o = o0 + ow * 16 + frow;
    f16 tmp[16];
#pragma unroll
    for (int g = 0; g < 16; ++g)
      tmp[g] = (f16)fmaxf(acc[g][r] * 0.14433756729740643f, 0.f);  // 1/sqrt(48)
    f16* dst = A2b + (size_t)b * 8192 + o * 16;
    *(half8*)dst = *(half8*)&tmp[0];
    *(half8*)(dst + 8) = *(half8*)&tmp[8];
  }
}

// gemm0: 256 blocks x 512 threads; tile M=128 x N=128; bid = s*64 + kc*4 + n.
// LDS: As[2][128*64] f16 (32 KB) + Bs[2][128*64] f32 (64 KB) = 96 KB.
__global__ __launch_bounds__(512) void gemm0(const f16* __restrict__ A,
                                             const float* __restrict__ W,
                                             float* __restrict__ P) {
  __shared__ __align__(16) f16 As[2][128 * 64];
  __shared__ __align__(16) float Bs[2][128 * 64];
  const int t = threadIdx.x;
  const int bid = blockIdx.x;
  constexpr int AK = 8192, ITERS = 8;
  const int s = bid >> 6;
  const int kc = (bid >> 2) & 15;
  const int n = bid & 3;
  const int kb0 = kc * (ITERS * 64);
  const f16* Ab = A + (size_t)s * 128 * AK + kb0;
  const int o0 = n << 7;

  const int wv = t >> 6, ln = t & 63;

#define STAGE(IT, BUF)                                                          \
  {                                                                             \
    _Pragma("unroll") for (int jj = 0; jj < 2; ++jj) { /* A: 128r x 8 granules */ \
      int rbase = wv * 16 + jj * 8;                                             \
      int r = rbase + (ln >> 3);                                                \
      int sg = (ln & 7) ^ (r & 7);                                              \
      GLOAD_LDS16(Ab + (size_t)r * AK + ((IT) << 6) + (sg << 3),                \
                  &As[BUF][rbase << 6]);                                        \
    }                                                                           \
    _Pragma("unroll") for (int jj = 0; jj < 4; ++jj) { /* B: 128r x 16 granules */ \
      int rbase = wv * 16 + jj * 4;                                             \
      int r = rbase + (ln >> 4);                                                \
      int sg = (ln & 15) ^ (r & 7);                                             \
      int k = kb0 + ((IT) << 6) + (sg << 2);                                    \
      const float* gp = W + (size_t)(o0 + r) * 32768 + ((k >> 4) << 6) +        \
                        (s << 4) + (k & 15);                                    \
      GLOAD_LDS16(gp, &Bs[BUF][rbase << 6]);                                    \
    }                                                                           \
  }

  const int wr = wv >> 2, wc = wv & 3;  // 2m x 4n waves, each 64 x 32
  const int frow = ln & 15, fr4 = ln >> 4;
  f32x4 acc[4][2] = {};

#define COMPUTE(BUF)                                                            \
  _Pragma("unroll") for (int ks = 0; ks < 2; ++ks) {                            \
    half8 a[4];                                                                 \
    _Pragma("unroll") for (int mi = 0; mi < 4; ++mi) {                          \
      int r = wr * 64 + mi * 16 + frow;                                         \
      int gl = ((ks << 2) + fr4) ^ (r & 7);                                     \
      a[mi] = *(const half8*)&As[BUF][(r << 6) + (gl << 3)];                    \
    }                                                                           \
    _Pragma("unroll") for (int ni = 0; ni < 2; ++ni) {                          \
      int r = wc * 32 + ni * 16 + frow;                                         \
      int s0 = (ks << 3) + (fr4 << 1);                                          \
      float4 f0 = *(const float4*)&Bs[BUF][(r << 6) + ((s0 ^ (r & 7)) << 2)];   \
      float4 f1 = *(const float4*)&Bs[BUF][(r << 6) + (((s0 + 1) ^ (r & 7)) << 2)]; \
      half8 hb;                                                                 \
      hb[0] = (f16)f0.x; hb[1] = (f16)f0.y; hb[2] = (f16)f0.z; hb[3] = (f16)f0.w; \
      hb[4] = (f16)f1.x; hb[5] = (f16)f1.y; hb[6] = (f16)f1.z; hb[7] = (f16)f1.w; \
      _Pragma("unroll") for (int mi = 0; mi < 4; ++mi)                          \
        acc[mi][ni] = __builtin_amdgcn_mfma_f32_16x16x32_f16(a[mi], hb, acc[mi][ni], 0, 0, 0); \
    }                                                                           \
  }

  STAGE(0, 0)
#pragma unroll
  for (int it = 0; it < ITERS; ++it) {
    const int cur = it & 1;
    if (it + 1 < ITERS) {
      STAGE(it + 1, cur ^ 1)  // 6 more in flight (12 total)
      asm volatile("s_waitcnt vmcnt(6)" ::: "memory");  // cur's 6 landed
    } else {
      asm volatile("s_waitcnt vmcnt(0)" ::: "memory");
    }
    __builtin_amdgcn_s_barrier();
    __builtin_amdgcn_sched_barrier(0);
    COMPUTE(cur)
    __builtin_amdgcn_sched_barrier(0);
    __builtin_amdgcn_s_barrier();
  }

  float* Pb = P + (size_t)((kc << 2) + s) * 65536;
#pragma unroll
  for (int mi = 0; mi < 4; ++mi)
#pragma unroll
    for (int ni = 0; ni < 2; ++ni)
#pragma unroll
      for (int r = 0; r < 4; ++r) {
        int gm = wr * 64 + mi * 16 + fr4 * 4 + r;
        int gn = o0 + wc * 32 + ni * 16 + frow;
        Pb[(size_t)gm * 512 + gn] = acc[mi][ni][r];
      }
#undef STAGE
#undef COMPUTE
}

// gemm1: R12 config (128 blocks, N=64 tile, K=2048, splitK=16).
__global__ __launch_bounds__(256) void gemm1(const f16* __restrict__ A,
                                             const float* __restrict__ W,
                                             float* __restrict__ P) {
  __shared__ __align__(16) f16 As[2][128 * 64];
  __shared__ __align__(16) float Bs[2][64 * 64];
  const int t = threadIdx.x;
  const int bid = blockIdx.x;
  constexpr int AK = 2048, ITERS = 2;
  const int kc = bid >> 3;
  const int n = bid & 7;
  const int kb0 = kc * (ITERS * 64);
  const f16* Ab = A + kb0;
  const int o0 = n << 6;
  const int wv = t >> 6, ln = t & 63;
  const int a_r = (ln >> 3), a_sg0 = ln & 7;
  const int b_r = (ln >> 4), b_sg0 = ln & 15;

#define STAGE(IT, BUF)                                                          \
  {                                                                             \
    _Pragma("unroll") for (int jj = 0; jj < 4; ++jj) {                          \
      int rbase = wv * 32 + jj * 8;                                             \
      int r = rbase + a_r;                                                      \
      int sg = a_sg0 ^ (r & 7);                                                 \
      GLOAD_LDS16(Ab + (size_t)r * AK + ((IT) << 6) + (sg << 3),                \
                  &As[BUF][rbase << 6]);                                        \
    }                                                                           \
    _Pragma("unroll") for (int jj = 0; jj < 4; ++jj) {                          \
      int rbase = wv * 16 + jj * 4;                                             \
      int r = rbase + b_r;                                                      \
      int sg = b_sg0 ^ (r & 7);                                                 \
      const float* gp = W + (size_t)(o0 + r) * 2048 + kb0 + ((IT) << 6) + (sg << 2); \
      GLOAD_LDS16(gp, &Bs[BUF][rbase << 6]);                                    \
    }                                                                           \
  }

  const int wr = wv >> 1, wc = wv & 1;
  const int frow = ln & 15, fr4 = ln >> 4;
  f32x4 acc[4][2] = {};

#define COMPUTE(BUF)                                                            \
  _Pragma("unroll") for (int ks = 0; ks < 2; ++ks) {                            \
    half8 a[4];                                                                 \
    _Pragma("unroll") for (int mi = 0; mi < 4; ++mi) {                          \
      int r = wr * 64 + mi * 16 + frow;                                         \
      int gl = ((ks << 2) + fr4) ^ (r & 7);                                     \
      a[mi] = *(const half8*)&As[BUF][(r << 6) + (gl << 3)];                    \
    }                                                                           \
    _Pragma("unroll") for (int ni = 0; ni < 2; ++ni) {                          \
      int r = wc * 32 + ni * 16 + frow;                                         \
      int s0 = (ks << 3) + (fr4 << 1);                                          \
      float4 f0 = *(const float4*)&Bs[BUF][(r << 6) + ((s0 ^ (r & 7)) << 2)];   \
      float4 f1 = *(const float4*)&Bs[BUF][(r << 6) + (((s0 + 1) ^ (r & 7)) << 2)]; \
      half8 hb;                                                                 \
      hb[0] = (f16)f0.x; hb[1] = (f16)f0.y; hb[2] = (f16)f0.z; hb[3] = (f16)f0.w; \
      hb[4] = (f16)f1.x; hb[5] = (f16)f1.y; hb[6] = (f16)f1.z; hb[7] = (f16)f1.w; \
      _Pragma("unroll") for (int mi = 0; mi < 4; ++mi)                          \
        acc[mi][ni] = __builtin_amdgcn_mfma_f32_16x16x32_f16(a[mi], hb, acc[mi][ni], 0, 0, 0); \
    }                                                                           \
  }

  STAGE(0, 0)
#pragma unroll
  for (int it = 0; it < ITERS; ++it) {
    const int cur = it & 1;
    if (it + 1 < ITERS) {
      STAGE(it + 1, cur ^ 1)
      asm volatile("s_waitcnt vmcnt(8)" ::: "memory");
    } else {
      asm volatile("s_waitcnt vmcnt(0)" ::: "memory");
    }
    __builtin_amdgcn_s_barrier();
    __builtin_amdgcn_sched_barrier(0);
    COMPUTE(cur)
    __builtin_amdgcn_sched_barrier(0);
    __builtin_amdgcn_s_barrier();
  }

  float* Pb = P + (size_t)kc * 65536;
#pragma unroll
  for (int mi = 0; mi < 4; ++mi)
#pragma unroll
    for (int ni = 0; ni < 2; ++ni)
#pragma unroll
      for (int r = 0; r < 4; ++r) {
        int gm = wr * 64 + mi * 16 + fr4 * 4 + r;
        int gn = o0 + wc * 32 + ni * 16 + frow;
        Pb[(size_t)gm * 512 + gn] = acc[mi][ni][r];
      }
#undef STAGE
#undef COMPUTE
}

__global__ __launch_bounds__(256) void reduce2(const float* __restrict__ P2,
                                               f16* __restrict__ A3) {
  int idx = blockIdx.x * 256 + threadIdx.x;
  int og = idx & 127, b = idx >> 7;
  f16 outv[16];
#pragma unroll
  for (int s = 0; s < 4; ++s) {
    float4 acc = {0.f, 0.f, 0.f, 0.f};
#pragma unroll
    for (int kc = 0; kc < 16; ++kc) {
      float4 v = *(const float4*)(P2 + (size_t)((kc << 2) + s) * 65536 + b * 512 + og * 4);
      acc.x += v.x; acc.y += v.y; acc.z += v.z; acc.w += v.w;
    }
    outv[0 * 4 + s] = (f16)fmaxf(acc.x * 0.011048543456039805f, 0.f);  // 1/sqrt(8192)
    outv[1 * 4 + s] = (f16)fmaxf(acc.y * 0.011048543456039805f, 0.f);
    outv[2 * 4 + s] = (f16)fmaxf(acc.z * 0.011048543456039805f, 0.f);
    outv[3 * 4 + s] = (f16)fmaxf(acc.w * 0.011048543456039805f, 0.f);
  }
  f16* dst = A3 + (size_t)b * 2048 + og * 16;
  *(half8*)dst = *(half8*)&outv[0];
  *(half8*)(dst + 8) = *(half8*)&outv[8];
}

__global__ __launch_bounds__(256) void out_fused(const float* __restrict__ P3,
                                                 const float* __restrict__ beta,
                                                 float* __restrict__ out) {
  __shared__ float red[4];
  const int b = blockIdx.x, t = threadIdx.x;
  float acc = 0.f;
#pragma unroll
  for (int oi = 0; oi < 2; ++oi) {
    int o = (oi << 8) + t;
    float v = 0.f;
#pragma unroll
    for (int kc = 0; kc < 16; ++kc) v += P3[(size_t)kc * 65536 + b * 512 + o];
    acc += fmaxf(v * 0.022097086912079608f, 0.f) * beta[o];  // 1/sqrt(2048)
  }
#pragma unroll
  for (int off = 32; off > 0; off >>= 1) acc += __shfl_down(acc, off);
  if ((t & 63) == 0) red[t >> 6] = acc;
  __syncthreads();
  if (t == 0) out[b] = (red[0] + red[1] + red[2] + red[3]) * 0.044194173824159216f;
}

extern "C" void kernel_launch(void* const* d_in, const int* in_sizes, int n_in,
                              void* d_out, int out_size, void* d_ws, size_t ws_size,
                              hipStream_t stream) {
  const float* x    = (const float*)d_in[0];
  const float* w1   = (const float*)d_in[1];
  const float* w2   = (const float*)d_in[2];
  const float* w3   = (const float*)d_in[3];
  const float* beta = (const float*)d_in[4];
  float* out = (float*)d_out;

  char* wsb = (char*)d_ws;
  f16*   A2 = (f16*)wsb;                                     // 8 MiB
  float* P2 = (float*)(wsb + (8ull << 20));                  // 16 MiB
  f16*   A3 = (f16*)(wsb + (24ull << 20));                   // 0.5 MiB
  float* P3 = (float*)(wsb + (24ull << 20) + (1ull << 19));  // 4 MiB

  l1_mfma<<<dim3(16, 4, 4), 256, 0, stream>>>(x, w1, A2);
  gemm0<<<256, 512, 0, stream>>>(A2, w2, P2);
  reduce2<<<64, 256, 0, stream>>>(P2, A3);
  gemm1<<<128, 256, 0, stream>>>(A3, w3, P3);
  out_fused<<<128, 256, 0, stream>>>(P3, beta, out);
}

// Round 18
// 44.983 us; speedup vs baseline: 8.3473x; 1.0390x over previous
//
#include <hip/hip_runtime.h>

// LocNet2d on MFMA fp16, 5 dispatches (R17 structure + fp16 P2/P3 intermediates):
//   l1_mfma: R12-v3 (s2-cell block, staged once, coalesced A2 stores)
//   gemm0:   per-s GEMM M=128,N=512,K=8192, splitK=16, TILE N=128 (256 blocks x
//            512 thr), K-step 64, dbuf LDS, counted vmcnt(6), global_load_lds.
//            P2 stored fp16 (halves intermediate traffic).
//   reduce2: fp16 P2 -> fp32 accum -> A3 fp16, coalesced.
//   gemm1:   128 blocks, N=64, splitK=16 -> P3 fp16
//   out:     reduce P3 + head.

typedef _Float16 f16;
typedef _Float16 half8 __attribute__((ext_vector_type(8)));
typedef _Float16 half4 __attribute__((ext_vector_type(4)));
typedef float f32x4 __attribute__((ext_vector_type(4)));

#define SWZ(r, c) ((((r) << 6) + (c)) ^ (((r) & 7) << 3))
#define SWZL(r, c) ((((r) << 10) + (c)) ^ (((r) & 7) << 3))

#define GLOAD_LDS16(G, L)                                                     \
  __builtin_amdgcn_global_load_lds(                                           \
      (const __attribute__((address_space(1))) void*)(G),                     \
      (__attribute__((address_space(3))) void*)(L), 16, 0, 0)

__global__ __launch_bounds__(256) void l1_mfma(const float* __restrict__ x,
                                               const float* __restrict__ w1,
                                               f16* __restrict__ A2) {
  const int o0 = blockIdx.x << 5;
  const int s2 = blockIdx.y;
  const int b0 = blockIdx.z << 5;
  const int p2 = s2 >> 1, q2 = s2 & 1;
  __shared__ __align__(16) f16 Xs[32 * 1024];  // 64 KB
  __shared__ __align__(16) f16 Ws[32 * 1024];  // 64 KB
  const int t = threadIdx.x;
#pragma unroll
  for (int i = 0; i < 8; ++i) {
    int e = (i << 8) + t;
    int row = e >> 6, rem = e & 63, g = rem >> 2, j = rem & 3;
    half4 z = {};
    *(half4*)&Xs[SWZL(row, g * 64 + 48 + j * 4)] = z;
    *(half4*)&Ws[SWZL(row, g * 64 + 48 + j * 4)] = z;
  }
#pragma unroll
  for (int i = 0; i < 24; ++i) {
    int fl = (i << 8) + t;
    int b = fl / 192, rem = fl % 192;
    int c = rem >> 6, rem2 = rem & 63;
    int a = rem2 >> 4, fi = (rem2 >> 2) & 3, bq = rem2 & 3;
    float4 v = *(const float4*)(x + ((size_t)(b0 + b) * 3 + c) * 1024 +
                                (p2 * 16 + a * 4 + fi) * 32 + q2 * 16 + bq * 4);
    half4 h;
    h[0] = (f16)v.x; h[1] = (f16)v.y; h[2] = (f16)v.z; h[3] = (f16)v.w;
    *(half4*)&Xs[SWZL(b, (a * 4 + bq) * 64 + c * 16 + fi * 4)] = h;
  }
#pragma unroll
  for (int i = 0; i < 24; ++i) {
    int fl = (i << 8) + t;
    int o = fl / 192, rem = fl % 192;
    int c = rem >> 6, rem2 = rem & 63;
    int g = rem2 >> 2, f4 = rem2 & 3;
    float4 v = *(const float4*)(w1 + (size_t)(o0 + o) * 3072 + c * 1024 +
                                (p2 * 4 + (g >> 2)) * 128 + (q2 * 4 + (g & 3)) * 16 + f4 * 4);
    half4 h;
    h[0] = (f16)v.x; h[1] = (f16)v.y; h[2] = (f16)v.z; h[3] = (f16)v.w;
    *(half4*)&Ws[SWZL(o, g * 64 + c * 16 + f4 * 4)] = h;
  }
  __syncthreads();

  const int wv = t >> 6, ln = t & 63;
  const int bw = wv >> 1, ow = wv & 1;
  const int frow = ln & 15, fr4 = ln >> 4;
  f32x4 acc[16] = {};
#pragma unroll
  for (int g = 0; g < 16; ++g) {
#pragma unroll
    for (int ks = 0; ks < 2; ++ks) {
      half8 a = *(const half8*)&Xs[SWZL(bw * 16 + frow, g * 64 + ks * 32 + fr4 * 8)];
      half8 b = *(const half8*)&Ws[SWZL(ow * 16 + frow, g * 64 + ks * 32 + fr4 * 8)];
      acc[g] = __builtin_amdgcn_mfma_f32_16x16x32_f16(a, b, acc[g], 0, 0, 0);
    }
  }
  f16* A2b = A2 + (size_t)s2 * 128 * 8192;
#pragma unroll
  for (int r = 0; r < 4; ++r) {
    int b = b0 + bw * 16 + fr4 * 4 + r;
    int o = o0 + ow * 16 + frow;
    f16 tmp[16];
#pragma unroll
    for (int g = 0; g < 16; ++g)
      tmp[g] = (f16)fmaxf(acc[g][r] * 0.14433756729740643f, 0.f);  // 1/sqrt(48)
    f16* dst = A2b + (size_t)b * 8192 + o * 16;
    *(half8*)dst = *(half8*)&tmp[0];
    *(half8*)(dst + 8) = *(half8*)&tmp[8];
  }
}

// gemm0: 256 blocks x 512 threads; tile M=128 x N=128; bid = s*64 + kc*4 + n.
__global__ __launch_bounds__(512) void gemm0(const f16* __restrict__ A,
                                             const float* __restrict__ W,
                                             f16* __restrict__ P) {
  __shared__ __align__(16) f16 As[2][128 * 64];
  __shared__ __align__(16) float Bs[2][128 * 64];
  const int t = threadIdx.x;
  const int bid = blockIdx.x;
  constexpr int AK = 8192, ITERS = 8;
  const int s = bid >> 6;
  const int kc = (bid >> 2) & 15;
  const int n = bid & 3;
  const int kb0 = kc * (ITERS * 64);
  const f16* Ab = A + (size_t)s * 128 * AK + kb0;
  const int o0 = n << 7;

  const int wv = t >> 6, ln = t & 63;

#define STAGE(IT, BUF)                                                          \
  {                                                                             \
    _Pragma("unroll") for (int jj = 0; jj < 2; ++jj) {                          \
      int rbase = wv * 16 + jj * 8;                                             \
      int r = rbase + (ln >> 3);                                                \
      int sg = (ln & 7) ^ (r & 7);                                              \
      GLOAD_LDS16(Ab + (size_t)r * AK + ((IT) << 6) + (sg << 3),                \
                  &As[BUF][rbase << 6]);                                        \
    }                                                                           \
    _Pragma("unroll") for (int jj = 0; jj < 4; ++jj) {                          \
      int rbase = wv * 16 + jj * 4;                                             \
      int r = rbase + (ln >> 4);                                                \
      int sg = (ln & 15) ^ (r & 7);                                             \
      int k = kb0 + ((IT) << 6) + (sg << 2);                                    \
      const float* gp = W + (size_t)(o0 + r) * 32768 + ((k >> 4) << 6) +        \
                        (s << 4) + (k & 15);                                    \
      GLOAD_LDS16(gp, &Bs[BUF][rbase << 6]);                                    \
    }                                                                           \
  }

  const int wr = wv >> 2, wc = wv & 3;  // 2m x 4n waves, each 64 x 32
  const int frow = ln & 15, fr4 = ln >> 4;
  f32x4 acc[4][2] = {};

#define COMPUTE(BUF)                                                            \
  _Pragma("unroll") for (int ks = 0; ks < 2; ++ks) {                            \
    half8 a[4];                                                                 \
    _Pragma("unroll") for (int mi = 0; mi < 4; ++mi) {                          \
      int r = wr * 64 + mi * 16 + frow;                                         \
      int gl = ((ks << 2) + fr4) ^ (r & 7);                                     \
      a[mi] = *(const half8*)&As[BUF][(r << 6) + (gl << 3)];                    \
    }                                                                           \
    _Pragma("unroll") for (int ni = 0; ni < 2; ++ni) {                          \
      int r = wc * 32 + ni * 16 + frow;                                         \
      int s0 = (ks << 3) + (fr4 << 1);                                          \
      float4 f0 = *(const float4*)&Bs[BUF][(r << 6) + ((s0 ^ (r & 7)) << 2)];   \
      float4 f1 = *(const float4*)&Bs[BUF][(r << 6) + (((s0 + 1) ^ (r & 7)) << 2)]; \
      half8 hb;                                                                 \
      hb[0] = (f16)f0.x; hb[1] = (f16)f0.y; hb[2] = (f16)f0.z; hb[3] = (f16)f0.w; \
      hb[4] = (f16)f1.x; hb[5] = (f16)f1.y; hb[6] = (f16)f1.z; hb[7] = (f16)f1.w; \
      _Pragma("unroll") for (int mi = 0; mi < 4; ++mi)                          \
        acc[mi][ni] = __builtin_amdgcn_mfma_f32_16x16x32_f16(a[mi], hb, acc[mi][ni], 0, 0, 0); \
    }                                                                           \
  }

  STAGE(0, 0)
#pragma unroll
  for (int it = 0; it < ITERS; ++it) {
    const int cur = it & 1;
    if (it + 1 < ITERS) {
      STAGE(it + 1, cur ^ 1)
      asm volatile("s_waitcnt vmcnt(6)" ::: "memory");
    } else {
      asm volatile("s_waitcnt vmcnt(0)" ::: "memory");
    }
    __builtin_amdgcn_s_barrier();
    __builtin_amdgcn_sched_barrier(0);
    COMPUTE(cur)
    __builtin_amdgcn_sched_barrier(0);
    __builtin_amdgcn_s_barrier();
  }

  f16* Pb = P + (size_t)((kc << 2) + s) * 65536;
#pragma unroll
  for (int mi = 0; mi < 4; ++mi)
#pragma unroll
    for (int ni = 0; ni < 2; ++ni)
#pragma unroll
      for (int r = 0; r < 4; ++r) {
        int gm = wr * 64 + mi * 16 + fr4 * 4 + r;
        int gn = o0 + wc * 32 + ni * 16 + frow;
        Pb[(size_t)gm * 512 + gn] = (f16)acc[mi][ni][r];
      }
#undef STAGE
#undef COMPUTE
}

// gemm1: 128 blocks, N=64 tile, K=2048, splitK=16; P3 fp16.
__global__ __launch_bounds__(256) void gemm1(const f16* __restrict__ A,
                                             const float* __restrict__ W,
                                             f16* __restrict__ P) {
  __shared__ __align__(16) f16 As[2][128 * 64];
  __shared__ __align__(16) float Bs[2][64 * 64];
  const int t = threadIdx.x;
  const int bid = blockIdx.x;
  constexpr int AK = 2048, ITERS = 2;
  const int kc = bid >> 3;
  const int n = bid & 7;
  const int kb0 = kc * (ITERS * 64);
  const f16* Ab = A + kb0;
  const int o0 = n << 6;
  const int wv = t >> 6, ln = t & 63;
  const int a_r = (ln >> 3), a_sg0 = ln & 7;
  const int b_r = (ln >> 4), b_sg0 = ln & 15;

#define STAGE(IT, BUF)                                                          \
  {                                                                             \
    _Pragma("unroll") for (int jj = 0; jj < 4; ++jj) {                          \
      int rbase = wv * 32 + jj * 8;                                             \
      int r = rbase + a_r;                                                      \
      int sg = a_sg0 ^ (r & 7);                                                 \
      GLOAD_LDS16(Ab + (size_t)r * AK + ((IT) << 6) + (sg << 3),                \
                  &As[BUF][rbase << 6]);                                        \
    }                                                                           \
    _Pragma("unroll") for (int jj = 0; jj < 4; ++jj) {                          \
      int rbase = wv * 16 + jj * 4;                                             \
      int r = rbase + b_r;                                                      \
      int sg = b_sg0 ^ (r & 7);                                                 \
      const float* gp = W + (size_t)(o0 + r) * 2048 + kb0 + ((IT) << 6) + (sg << 2); \
      GLOAD_LDS16(gp, &Bs[BUF][rbase << 6]);                                    \
    }                                                                           \
  }

  const int wr = wv >> 1, wc = wv & 1;
  const int frow = ln & 15, fr4 = ln >> 4;
  f32x4 acc[4][2] = {};

#define COMPUTE(BUF)                                                            \
  _Pragma("unroll") for (int ks = 0; ks < 2; ++ks) {                            \
    half8 a[4];                                                                 \
    _Pragma("unroll") for (int mi = 0; mi < 4; ++mi) {                          \
      int r = wr * 64 + mi * 16 + frow;                                         \
      int gl = ((ks << 2) + fr4) ^ (r & 7);                                     \
      a[mi] = *(const half8*)&As[BUF][(r << 6) + (gl << 3)];                    \
    }                                                                           \
    _Pragma("unroll") for (int ni = 0; ni < 2; ++ni) {                          \
      int r = wc * 32 + ni * 16 + frow;                                         \
      int s0 = (ks << 3) + (fr4 << 1);                                          \
      float4 f0 = *(const float4*)&Bs[BUF][(r << 6) + ((s0 ^ (r & 7)) << 2)];   \
      float4 f1 = *(const float4*)&Bs[BUF][(r << 6) + (((s0 + 1) ^ (r & 7)) << 2)]; \
      half8 hb;                                                                 \
      hb[0] = (f16)f0.x; hb[1] = (f16)f0.y; hb[2] = (f16)f0.z; hb[3] = (f16)f0.w; \
      hb[4] = (f16)f1.x; hb[5] = (f16)f1.y; hb[6] = (f16)f1.z; hb[7] = (f16)f1.w; \
      _Pragma("unroll") for (int mi = 0; mi < 4; ++mi)                          \
        acc[mi][ni] = __builtin_amdgcn_mfma_f32_16x16x32_f16(a[mi], hb, acc[mi][ni], 0, 0, 0); \
    }                                                                           \
  }

  STAGE(0, 0)
#pragma unroll
  for (int it = 0; it < ITERS; ++it) {
    const int cur = it & 1;
    if (it + 1 < ITERS) {
      STAGE(it + 1, cur ^ 1)
      asm volatile("s_waitcnt vmcnt(8)" ::: "memory");
    } else {
      asm volatile("s_waitcnt vmcnt(0)" ::: "memory");
    }
    __builtin_amdgcn_s_barrier();
    __builtin_amdgcn_sched_barrier(0);
    COMPUTE(cur)
    __builtin_amdgcn_sched_barrier(0);
    __builtin_amdgcn_s_barrier();
  }

  f16* Pb = P + (size_t)kc * 65536;
#pragma unroll
  for (int mi = 0; mi < 4; ++mi)
#pragma unroll
    for (int ni = 0; ni < 2; ++ni)
#pragma unroll
      for (int r = 0; r < 4; ++r) {
        int gm = wr * 64 + mi * 16 + fr4 * 4 + r;
        int gn = o0 + wc * 32 + ni * 16 + frow;
        Pb[(size_t)gm * 512 + gn] = (f16)acc[mi][ni][r];
      }
#undef STAGE
#undef COMPUTE
}

__global__ __launch_bounds__(256) void reduce2(const f16* __restrict__ P2,
                                               f16* __restrict__ A3) {
  int idx = blockIdx.x * 256 + threadIdx.x;
  int og = idx & 127, b = idx >> 7;
  f16 outv[16];
#pragma unroll
  for (int s = 0; s < 4; ++s) {
    float a0 = 0.f, a1 = 0.f, a2 = 0.f, a3 = 0.f;
#pragma unroll
    for (int kc = 0; kc < 16; ++kc) {
      half4 v = *(const half4*)(P2 + (size_t)((kc << 2) + s) * 65536 + b * 512 + og * 4);
      a0 += (float)v[0]; a1 += (float)v[1]; a2 += (float)v[2]; a3 += (float)v[3];
    }
    outv[0 * 4 + s] = (f16)fmaxf(a0 * 0.011048543456039805f, 0.f);  // 1/sqrt(8192)
    outv[1 * 4 + s] = (f16)fmaxf(a1 * 0.011048543456039805f, 0.f);
    outv[2 * 4 + s] = (f16)fmaxf(a2 * 0.011048543456039805f, 0.f);
    outv[3 * 4 + s] = (f16)fmaxf(a3 * 0.011048543456039805f, 0.f);
  }
  f16* dst = A3 + (size_t)b * 2048 + og * 16;
  *(half8*)dst = *(half8*)&outv[0];
  *(half8*)(dst + 8) = *(half8*)&outv[8];
}

__global__ __launch_bounds__(256) void out_fused(const f16* __restrict__ P3,
                                                 const float* __restrict__ beta,
                                                 float* __restrict__ out) {
  __shared__ float red[4];
  const int b = blockIdx.x, t = threadIdx.x;
  float acc = 0.f;
#pragma unroll
  for (int oi = 0; oi < 2; ++oi) {
    int o = (oi << 8) + t;
    float v = 0.f;
#pragma unroll
    for (int kc = 0; kc < 16; ++kc) v += (float)P3[(size_t)kc * 65536 + b * 512 + o];
    acc += fmaxf(v * 0.022097086912079608f, 0.f) * beta[o];  // 1/sqrt(2048)
  }
#pragma unroll
  for (int off = 32; off > 0; off >>= 1) acc += __shfl_down(acc, off);
  if ((t & 63) == 0) red[t >> 6] = acc;
  __syncthreads();
  if (t == 0) out[b] = (red[0] + red[1] + red[2] + red[3]) * 0.044194173824159216f;
}

extern "C" void kernel_launch(void* const* d_in, const int* in_sizes, int n_in,
                              void* d_out, int out_size, void* d_ws, size_t ws_size,
                              hipStream_t stream) {
  const float* x    = (const float*)d_in[0];
  const float* w1   = (const float*)d_in[1];
  const float* w2   = (const float*)d_in[2];
  const float* w3   = (const float*)d_in[3];
  const float* beta = (const float*)d_in[4];
  float* out = (float*)d_out;

  char* wsb = (char*)d_ws;
  f16* A2 = (f16*)wsb;                                     // 8 MiB
  f16* P2 = (f16*)(wsb + (8ull << 20));                    // 8 MiB (fp16)
  f16* A3 = (f16*)(wsb + (16ull << 20));                   // 0.5 MiB
  f16* P3 = (f16*)(wsb + (16ull << 20) + (1ull << 19));    // 2 MiB (fp16)

  l1_mfma<<<dim3(16, 4, 4), 256, 0, stream>>>(x, w1, A2);
  gemm0<<<256, 512, 0, stream>>>(A2, w2, P2);
  reduce2<<<64, 256, 0, stream>>>(P2, A3);
  gemm1<<<128, 256, 0, stream>>>(A3, w3, P3);
  out_fused<<<128, 256, 0, stream>>>(P3, beta, out);
}